// Round 2
// baseline (6480.796 us; speedup 1.0000x reference)
//
#include <hip/hip_runtime.h>

// ---------------------------------------------------------------------------
// GeneralRNN: h_t = hmlp([h_{t-1}, x_t]), y_t = ymlp(h_t)
// B=256, S=1024, D_IN=64, H=256, W_H=512, W_Y=256, D_OUT=64
// R2: operand-swapped MFMA (z1^T = W1h^T hx^T, h^T = W2h^T a1^T) so outputs
//     land 4-consecutive-per-row -> b64 LDS writes + float4 global stores;
//     T2 XOR swizzle (elem ^= swz(row)) with stride 320/512 -> <=2-way banks.
//     W1h kc5..9 resident (80 VGPR), kc0..4 streamed; W2h kc0..7 resident,
//     kc8..15 in LDS (staged once). x prefetched one step ahead.
// ---------------------------------------------------------------------------

typedef __bf16 bf16;
typedef __bf16 bf16x2 __attribute__((ext_vector_type(2)));
typedef __bf16 bf16x4 __attribute__((ext_vector_type(4)));
typedef __bf16 bf16x8 __attribute__((ext_vector_type(8)));
typedef float  f32x4  __attribute__((ext_vector_type(4)));

#define MFMA16(a, b, c) __builtin_amdgcn_mfma_f32_16x16x32_bf16((a), (b), (c), 0, 0, 0)

static constexpr int Bz = 256, Sq = 1024, DIN = 64, H = 256, WH = 512, WY = 256, DOUT = 64;
static constexpr int OUTS_N = Bz * Sq * DOUT;
static constexpr int HID_T  = Bz * H;

// packed bf16 fragment segments in ws (element offsets)
static constexpr int W1H_OFF = 0;
static constexpr int W1H_CNT = (H + DIN) * WH;          // [nt32][kc10][lane64][j8]
static constexpr int W2H_OFF = W1H_OFF + W1H_CNT;
static constexpr int W2H_CNT = WH * H;                  // [nt16][kc16][lane][j]
static constexpr int W1Y_OFF = W2H_OFF + W2H_CNT;
static constexpr int W1Y_CNT = H * WY;                  // [nt16][kc8][lane][j]
static constexpr int W2Y_OFF = W1Y_OFF + W1Y_CNT;
static constexpr int W2Y_CNT = WY * DOUT;               // [nt4][kc8][lane][j]
static constexpr int PACK_TOTAL = W2Y_OFF + W2Y_CNT;

// LDS strides: row stride multiple of 128B so banks depend only on in-row
// offset; XOR-swizzle spreads rows. (T2)
static constexpr int HX_LD = 320;
static constexpr int A1_LD = 512;

__device__ __forceinline__ float silu_f(float z) { return z / (1.0f + __expf(-z)); }
// element-offset XOR (units of 8 elems = 16B); rows r and r+8 differ too
__device__ __forceinline__ int swz8(int row) { return ((row ^ (row >> 3)) & 7) << 3; }

__device__ __forceinline__ bf16x4 silu4(f32x4 v) {
    bf16x4 p;
    p[0] = (bf16)silu_f(v[0]); p[1] = (bf16)silu_f(v[1]);
    p[2] = (bf16)silu_f(v[2]); p[3] = (bf16)silu_f(v[3]);
    return p;
}

// ---------------------------------------------------------------------------
// K0: pack all weights into bf16 fragment order.
// frag[nt][kc][lane][j] = W[kc*32 + (L>>4)*8 + j][nt*16 + (L&15)]
// This is simultaneously the B-frag of W and the A-frag of W^T.
// ---------------------------------------------------------------------------
__global__ void prep_pack(const float* __restrict__ W1h, const float* __restrict__ W2h,
                          const float* __restrict__ W1y, const float* __restrict__ W2y,
                          bf16* __restrict__ ws) {
    int idx = blockIdx.x * 256 + threadIdx.x;
    if (idx >= PACK_TOTAL) return;
    int r = idx;
    const float* src; int row, col, ld;
    if (idx < W2H_OFF) {                               // W1h [320][512]
        int j = r & 7; r >>= 3; int L = r & 63; r >>= 6;
        int kc = r % 10, nt = r / 10;
        row = kc * 32 + ((L >> 4) << 3) + j; col = nt * 16 + (L & 15);
        src = W1h; ld = WH;
    } else if (idx < W1Y_OFF) {                        // W2h [512][256]
        r -= W2H_OFF;
        int j = r & 7; r >>= 3; int L = r & 63; r >>= 6;
        int kc = r & 15, nt = r >> 4;
        row = kc * 32 + ((L >> 4) << 3) + j; col = nt * 16 + (L & 15);
        src = W2h; ld = H;
    } else if (idx < W2Y_OFF) {                        // W1y [256][256]
        r -= W1Y_OFF;
        int j = r & 7; r >>= 3; int L = r & 63; r >>= 6;
        int kc = r & 7, nt = r >> 3;
        row = kc * 32 + ((L >> 4) << 3) + j; col = nt * 16 + (L & 15);
        src = W1y; ld = WY;
    } else {                                           // W2y [256][64]
        r -= W2Y_OFF;
        int j = r & 7; r >>= 3; int L = r & 63; r >>= 6;
        int kc = r & 7, nt = r >> 3;
        row = kc * 32 + ((L >> 4) << 3) + j; col = nt * 16 + (L & 15);
        src = W2y; ld = DOUT;
    }
    ws[idx] = (bf16)src[row * ld + col];
}

// ---------------------------------------------------------------------------
// K1: recurrence. grid=16, block=512 (8 waves).
// ---------------------------------------------------------------------------
__global__ __launch_bounds__(512, 2) void rnn_recur(
        const float* __restrict__ x, const float* __restrict__ b1h,
        const float* __restrict__ b2h, const bf16* __restrict__ ws,
        float* __restrict__ out) {
    // 131072 + 10240 + 16384 = 157696 B <= 163840 B LDS
    __shared__ __align__(16) bf16 w2l[16 * 8 * 64 * 8]; // W2h kc8..15 frags, 128KB
    __shared__ __align__(16) bf16 hx_s[16 * HX_LD];     // [batch16][h256 | x64]
    __shared__ __align__(16) bf16 a1_s[16 * A1_LD];     // [batch16][512]

    const int tid = threadIdx.x;
    const int wv = tid >> 6, ln = tid & 63;
    const int quad = ln >> 4, l16 = ln & 15;
    const int swl = swz8(l16);
    const int wgb = blockIdx.x;
    float* hid = out + OUTS_N;

    // h0 = 0: zero whole hx buffer (incl. x region) and hiddens[0] slab
    for (int i = tid; i < 16 * HX_LD; i += 512) hx_s[i] = (bf16)0.0f;
    for (int i = tid; i < 16 * 256; i += 512) {
        int m = i >> 8, c = i & 255;
        hid[(wgb * 16 + m) * H + c] = 0.0f;
    }

    // stage W2h kc8..15 into LDS once: [nt16][kc8][lane][j8] (linear, 2-way free)
    for (int u = tid; u < 16 * 8 * 64; u += 512) {
        int nt = u >> 9, kc8 = (u >> 6) & 7, lu = u & 63;
        *(bf16x8*)(w2l + ((size_t)u << 3)) =
            *(const bf16x8*)(ws + W2H_OFF + (((nt * 16 + 8 + kc8) * 64 + lu) << 3));
    }

    // resident W1h kc5..9: wave wv owns mtiles {4wv..4wv+3} -> 80 VGPRs
    bf16x8 w1r[5][4];
#pragma unroll
    for (int kci = 0; kci < 5; kci++)
#pragma unroll
        for (int i = 0; i < 4; i++)
            w1r[kci][i] = *(const bf16x8*)(ws + W1H_OFF + ((((wv * 4 + i) * 10 + 5 + kci) * 64 + ln) << 3));

    // resident W2h kc0..7: wave wv owns mtiles {2wv, 2wv+1} -> 64 VGPRs
    bf16x8 w2f[8][2];
#pragma unroll
    for (int kc = 0; kc < 8; kc++)
#pragma unroll
        for (int i = 0; i < 2; i++)
            w2f[kc][i] = *(const bf16x8*)(ws + W2H_OFF + ((((wv * 2 + i) * 16 + kc) * 64 + ln) << 3));

    // biases as float4 along the output-column direction (swapped layout:
    // lane reg r holds col (tile*16 + 4*quad + r))
    f32x4 bs1[4], bs2[2];
#pragma unroll
    for (int i = 0; i < 4; i++) {
        float4 v = *(const float4*)(b1h + (wv * 4 + i) * 16 + quad * 4);
        bs1[i][0] = v.x; bs1[i][1] = v.y; bs1[i][2] = v.z; bs1[i][3] = v.w;
    }
#pragma unroll
    for (int i = 0; i < 2; i++) {
        float4 v = *(const float4*)(b2h + (wv * 2 + i) * 16 + quad * 4);
        bs2[i][0] = v.x; bs2[i][1] = v.y; bs2[i][2] = v.z; bs2[i][3] = v.w;
    }

    // x staging role: thread -> (row mrow, 2 contiguous x elements)
    const int mrow = tid >> 5;
    const int i2 = (tid & 31) * 2;
    const float* xrow = x + (size_t)(wgb * 16 + mrow) * (Sq * DIN) + i2;
    const int xoff = mrow * HX_LD + ((256 + i2) ^ swz8(mrow));

    // streamed W1h kc0..4 via two rotating 4-frag buffers (32 VGPRs)
#define W1HP(i, kc) ((const bf16x8*)(ws + W1H_OFF + ((((wv * 4 + (i)) * 10 + (kc)) * 64 + ln) << 3)))
    bf16x8 sA[4], sB[4];
#pragma unroll
    for (int i = 0; i < 4; i++) sA[i] = *W1HP(i, 0);
#pragma unroll
    for (int i = 0; i < 4; i++) sB[i] = *W1HP(i, 1);

    float2 xv = *(const float2*)(xrow);   // x_0 prefetched

#define LDHX(kc) (*(const bf16x8*)(hx_s + l16 * HX_LD + (((kc) * 32 + quad * 8) ^ swl)))
#define LDA1(kc) (*(const bf16x8*)(a1_s + l16 * A1_LD + (((kc) * 32 + quad * 8) ^ swl)))

#pragma unroll 1
    for (int t = 0; t < Sq; t++) {
        // stage prefetched x_t -> hx[:,256:320] (swizzled)
        bf16x2 xp; xp[0] = (bf16)xv.x; xp[1] = (bf16)xv.y;
        *(bf16x2*)(hx_s + xoff) = xp;
        __syncthreads();   // (b): h + x staged, prior readers done

        // prefetch x_{t+1}
        xv = *(const float2*)(xrow + ((t + 1) & (Sq - 1)) * DIN);

        // ---- GEMM1 (swapped): z1^T = W1h^T hx^T; acc1[i] -> cols (4wv+i)*16+4q+r,
        //      batch row l16. Bias pre-loaded into accumulator. ----
        f32x4 acc1[4] = {bs1[0], bs1[1], bs1[2], bs1[3]};
        bf16x8 a;
        a = LDHX(0);
#pragma unroll
        for (int i = 0; i < 4; i++) acc1[i] = MFMA16(sA[i], a, acc1[i]);
#pragma unroll
        for (int i = 0; i < 4; i++) sA[i] = *W1HP(i, 2);
        a = LDHX(1);
#pragma unroll
        for (int i = 0; i < 4; i++) acc1[i] = MFMA16(sB[i], a, acc1[i]);
#pragma unroll
        for (int i = 0; i < 4; i++) sB[i] = *W1HP(i, 3);
        a = LDHX(5);
#pragma unroll
        for (int i = 0; i < 4; i++) acc1[i] = MFMA16(w1r[0][i], a, acc1[i]);
        a = LDHX(6);
#pragma unroll
        for (int i = 0; i < 4; i++) acc1[i] = MFMA16(w1r[1][i], a, acc1[i]);
        a = LDHX(2);
#pragma unroll
        for (int i = 0; i < 4; i++) acc1[i] = MFMA16(sA[i], a, acc1[i]);
#pragma unroll
        for (int i = 0; i < 4; i++) sA[i] = *W1HP(i, 4);
        a = LDHX(3);
#pragma unroll
        for (int i = 0; i < 4; i++) acc1[i] = MFMA16(sB[i], a, acc1[i]);
        a = LDHX(7);
#pragma unroll
        for (int i = 0; i < 4; i++) acc1[i] = MFMA16(w1r[2][i], a, acc1[i]);
        a = LDHX(4);
#pragma unroll
        for (int i = 0; i < 4; i++) acc1[i] = MFMA16(sA[i], a, acc1[i]);
        a = LDHX(8);
#pragma unroll
        for (int i = 0; i < 4; i++) acc1[i] = MFMA16(w1r[3][i], a, acc1[i]);
        a = LDHX(9);
#pragma unroll
        for (int i = 0; i < 4; i++) acc1[i] = MFMA16(w1r[4][i], a, acc1[i]);

        // silu -> a1: one b64 write per i (4 consecutive cols of row l16)
#pragma unroll
        for (int i = 0; i < 4; i++)
            *(bf16x4*)(a1_s + l16 * A1_LD + (((wv * 4 + i) * 16 + quad * 4) ^ swl)) = silu4(acc1[i]);
        __syncthreads();   // (d): a1 complete, hx readers done

        // issue next step's streamed kc0/kc1 (distance ~= whole GEMM2)
#pragma unroll
        for (int i = 0; i < 4; i++) sA[i] = *W1HP(i, 0);
#pragma unroll
        for (int i = 0; i < 4; i++) sB[i] = *W1HP(i, 1);

        // ---- GEMM2 (swapped): h^T = W2h^T a1^T; acc2[i] -> h cols (2wv+i)*16+4q+r ----
        f32x4 acc2[2] = {bs2[0], bs2[1]};
#pragma unroll
        for (int kc = 0; kc < 8; kc++) {
            a = LDA1(kc);
#pragma unroll
            for (int i = 0; i < 2; i++) acc2[i] = MFMA16(w2f[kc][i], a, acc2[i]);
        }
#pragma unroll
        for (int kc = 8; kc < 16; kc++) {
            a = LDA1(kc);
#pragma unroll
            for (int i = 0; i < 2; i++) {
                bf16x8 b = *(const bf16x8*)(w2l + ((((wv * 2 + i) * 8 + (kc - 8)) * 64 + ln) << 3));
                acc2[i] = MFMA16(b, a, acc2[i]);
            }
        }

        // write h: float4 -> hiddens[t+1], b64 bf16 -> LDS for next step
        float* hdst = hid + (size_t)(t + 1) * HID_T + (wgb * 16 + l16) * H;
#pragma unroll
        for (int i = 0; i < 2; i++) {
            float4 hv; hv.x = acc2[i][0]; hv.y = acc2[i][1]; hv.z = acc2[i][2]; hv.w = acc2[i][3];
            *(float4*)(hdst + (2 * wv + i) * 16 + quad * 4) = hv;
            bf16x4 p; p[0] = (bf16)hv.x; p[1] = (bf16)hv.y; p[2] = (bf16)hv.z; p[3] = (bf16)hv.w;
            *(bf16x4*)(hx_s + l16 * HX_LD + (((2 * wv + i) * 16 + quad * 4) ^ swl)) = p;
        }
        // no barrier: next x-stage writes hx[:,256:320] (disjoint); (b) guards reads
    }
#undef W1HP
#undef LDHX
#undef LDA1
}

// ---------------------------------------------------------------------------
// K2: output MLP over all (b,t). grid=4096 (b=g>>4, t0=(g&15)*64), block=256.
// Swapped GEMMs: b64 LDS writes, float4 output stores, swizzled hb.
// ---------------------------------------------------------------------------
__global__ __launch_bounds__(256) void rnn_ymlp(
        const float* __restrict__ b1y, const float* __restrict__ b2y,
        const bf16* __restrict__ ws, float* __restrict__ out) {
    __shared__ __align__(16) bf16 hb[64 * 256];   // h rows, later a2 rows (swizzled)

    const int tid = threadIdx.x, wv = tid >> 6, ln = tid & 63;
    const int quad = ln >> 4, l16 = ln & 15;
    const int g = blockIdx.x, b = g >> 4, t0 = (g & 15) * 64;
    const float* hid = out + OUTS_N;

    // stage h rows t0+1 .. t0+64 -> bf16 LDS (swizzled, b64 writes)
    {
        int r = tid >> 2, c0 = (tid & 3) * 64;
        const int swr = swz8(r);
        const float* srcr = hid + (size_t)(t0 + 1 + r) * HID_T + b * H + c0;
        bf16* drow = hb + r * 256;
#pragma unroll
        for (int jj = 0; jj < 16; jj++) {
            float4 v = *(const float4*)(srcr + jj * 4);
            bf16x4 p; p[0] = (bf16)v.x; p[1] = (bf16)v.y; p[2] = (bf16)v.z; p[3] = (bf16)v.w;
            *(bf16x4*)(drow + ((c0 + jj * 4) ^ swr)) = p;
        }
    }
    __syncthreads();

    // GEMM1 (swapped): z2^T = W1y^T hb^T. acc[i][nt]: cols (4wv+i)*16+4q+r,
    // rows nt*16+l16.
    f32x4 acc[4][4];
#pragma unroll
    for (int i = 0; i < 4; i++) {
        float4 v = *(const float4*)(b1y + (wv * 4 + i) * 16 + quad * 4);
        f32x4 bv; bv[0] = v.x; bv[1] = v.y; bv[2] = v.z; bv[3] = v.w;
#pragma unroll
        for (int nt = 0; nt < 4; nt++) acc[i][nt] = bv;
    }
#pragma unroll
    for (int kc = 0; kc < 8; kc++) {
        bf16x8 bb[4];
#pragma unroll
        for (int nt = 0; nt < 4; nt++) {
            int row = nt * 16 + l16;
            bb[nt] = *(const bf16x8*)(hb + row * 256 + ((kc * 32 + quad * 8) ^ swz8(row)));
        }
#pragma unroll
        for (int i = 0; i < 4; i++) {
            bf16x8 wf = *(const bf16x8*)(ws + W1Y_OFF + ((((wv * 4 + i) * 8 + kc) * 64 + ln) << 3));
#pragma unroll
            for (int nt = 0; nt < 4; nt++) acc[i][nt] = MFMA16(wf, bb[nt], acc[i][nt]);
        }
    }
    __syncthreads();   // all hb reads done before overwrite

    // silu -> a2 back into hb (b64 writes)
#pragma unroll
    for (int i = 0; i < 4; i++)
#pragma unroll
        for (int nt = 0; nt < 4; nt++) {
            int row = nt * 16 + l16;
            *(bf16x4*)(hb + row * 256 + ((((wv * 4 + i) * 16 + quad * 4)) ^ swz8(row))) = silu4(acc[i][nt]);
        }
    __syncthreads();

    // GEMM2 (swapped): y^T = W2y^T a2^T; wave wv owns dout tile wv.
    f32x4 acy[4];
    {
        float4 v = *(const float4*)(b2y + wv * 16 + quad * 4);
        f32x4 bv; bv[0] = v.x; bv[1] = v.y; bv[2] = v.z; bv[3] = v.w;
#pragma unroll
        for (int nt = 0; nt < 4; nt++) acy[nt] = bv;
    }
#pragma unroll
    for (int kc = 0; kc < 8; kc++) {
        bf16x8 wf = *(const bf16x8*)(ws + W2Y_OFF + (((wv * 8 + kc) * 64 + ln) << 3));
#pragma unroll
        for (int nt = 0; nt < 4; nt++) {
            int row = nt * 16 + l16;
            bf16x8 aa = *(const bf16x8*)(hb + row * 256 + ((kc * 32 + quad * 8) ^ swz8(row)));
            acy[nt] = MFMA16(wf, aa, acy[nt]);
        }
    }
    float* ob = out + (size_t)b * (Sq * DOUT);
#pragma unroll
    for (int nt = 0; nt < 4; nt++) {
        float4 v; v.x = acy[nt][0]; v.y = acy[nt][1]; v.z = acy[nt][2]; v.w = acy[nt][3];
        *(float4*)(ob + (size_t)(t0 + nt * 16 + l16) * DOUT + wv * 16 + quad * 4) = v;
    }
}

// ---------------------------------------------------------------------------
extern "C" void kernel_launch(void* const* d_in, const int* in_sizes, int n_in,
                              void* d_out, int out_size, void* d_ws, size_t ws_size,
                              hipStream_t stream) {
    (void)in_sizes; (void)n_in; (void)out_size; (void)ws_size;
    const float* x   = (const float*)d_in[0];
    const float* W1h = (const float*)d_in[1];
    const float* b1h = (const float*)d_in[2];
    const float* W2h = (const float*)d_in[3];
    const float* b2h = (const float*)d_in[4];
    const float* W1y = (const float*)d_in[5];
    const float* b1y = (const float*)d_in[6];
    const float* W2y = (const float*)d_in[7];
    const float* b2y = (const float*)d_in[8];
    float* out = (float*)d_out;
    bf16* ws = (bf16*)d_ws;

    prep_pack<<<(PACK_TOTAL + 255) / 256, 256, 0, stream>>>(W1h, W2h, W1y, W2y, ws);
    rnn_recur<<<16, 512, 0, stream>>>(x, b1h, b2h, ws, out);
    rnn_ymlp<<<4096, 256, 0, stream>>>(b1y, b2y, ws, out);
}

// Round 3
// 4554.487 us; speedup vs baseline: 1.4229x; 1.4229x over previous
//
#include <hip/hip_runtime.h>

// ---------------------------------------------------------------------------
// GeneralRNN: h_t = hmlp([h_{t-1}, x_t]), y_t = ymlp(h_t)
// B=256, S=1024, D_IN=64, H=256, W_H=512, W_Y=256, D_OUT=64
// R3: TRUE weight residency. R1/R2's "resident" VGPR fragments were silently
//     rematerialized by the compiler as per-step global loads (evidence:
//     VGPR_Count=128 while the design needed ~250) -> ~300KB/step/CU L2
//     re-stream dominated. Fix:
//       - asm volatile("" : "+v"(frag)) pins after load (opaque def, no remat)
//       - honest budget: pin W1h kc6..9 (64 VGPR) + W2h kc0..7 (64);
//         W2h kc8..15 in LDS (128KB); stream W1h kc0..5 (192KB/step) via 2
//         rotating buffers issued >=3 MFMA-groups ahead.
//       - biases in LDS (re-read per step; barrier blocks hoisting)
//       - h global store deferred across barrier (b) (carried in VGPRs)
//       - LDS strides back to 336/528 (R0 empirically fewest conflicts),
//         keep R2's operand-swap (vector b64 LDS writes, float4 h stores).
// ---------------------------------------------------------------------------

typedef __bf16 bf16;
typedef __bf16 bf16x2 __attribute__((ext_vector_type(2)));
typedef __bf16 bf16x4 __attribute__((ext_vector_type(4)));
typedef __bf16 bf16x8 __attribute__((ext_vector_type(8)));
typedef float  f32x4  __attribute__((ext_vector_type(4)));

#define MFMA16(a, b, c) __builtin_amdgcn_mfma_f32_16x16x32_bf16((a), (b), (c), 0, 0, 0)

static constexpr int Bz = 256, Sq = 1024, DIN = 64, H = 256, WH = 512, WY = 256, DOUT = 64;
static constexpr int OUTS_N = Bz * Sq * DOUT;
static constexpr int HID_T  = Bz * H;

// packed bf16 fragment segments in ws (element offsets)
static constexpr int W1H_OFF = 0;
static constexpr int W1H_CNT = (H + DIN) * WH;          // [nt32][kc10][lane64][j8]
static constexpr int W2H_OFF = W1H_OFF + W1H_CNT;
static constexpr int W2H_CNT = WH * H;                  // [nt16][kc16][lane][j]
static constexpr int W1Y_OFF = W2H_OFF + W2H_CNT;
static constexpr int W1Y_CNT = H * WY;                  // [nt16][kc8][lane][j]
static constexpr int W2Y_OFF = W1Y_OFF + W1Y_CNT;
static constexpr int W2Y_CNT = WY * DOUT;               // [nt4][kc8][lane][j]
static constexpr int PACK_TOTAL = W2Y_OFF + W2Y_CNT;

static constexpr int HX_LD = 336;   // 168 words, == 8 mod 32 (R0-proven)
static constexpr int A1_LD = 528;   // 264 words, == 8 mod 32

__device__ __forceinline__ float silu_f(float z) { return z / (1.0f + __expf(-z)); }

__device__ __forceinline__ bf16x8 bc8(f32x4 v) { return __builtin_bit_cast(bf16x8, v); }

__device__ __forceinline__ bf16x4 silu4(f32x4 v) {
    bf16x4 p;
    p[0] = (bf16)silu_f(v[0]); p[1] = (bf16)silu_f(v[1]);
    p[2] = (bf16)silu_f(v[2]); p[3] = (bf16)silu_f(v[3]);
    return p;
}

// ---------------------------------------------------------------------------
// K0: pack all weights into bf16 fragment order.
// frag[nt][kc][lane][j] = W[kc*32 + (L>>4)*8 + j][nt*16 + (L&15)]
// = B-frag of W and simultaneously A-frag of W^T.
// ---------------------------------------------------------------------------
__global__ void prep_pack(const float* __restrict__ W1h, const float* __restrict__ W2h,
                          const float* __restrict__ W1y, const float* __restrict__ W2y,
                          bf16* __restrict__ ws) {
    int idx = blockIdx.x * 256 + threadIdx.x;
    if (idx >= PACK_TOTAL) return;
    int r = idx;
    const float* src; int row, col, ld;
    if (idx < W2H_OFF) {                               // W1h [320][512]
        int j = r & 7; r >>= 3; int L = r & 63; r >>= 6;
        int kc = r % 10, nt = r / 10;
        row = kc * 32 + ((L >> 4) << 3) + j; col = nt * 16 + (L & 15);
        src = W1h; ld = WH;
    } else if (idx < W1Y_OFF) {                        // W2h [512][256]
        r -= W2H_OFF;
        int j = r & 7; r >>= 3; int L = r & 63; r >>= 6;
        int kc = r & 15, nt = r >> 4;
        row = kc * 32 + ((L >> 4) << 3) + j; col = nt * 16 + (L & 15);
        src = W2h; ld = H;
    } else if (idx < W2Y_OFF) {                        // W1y [256][256]
        r -= W1Y_OFF;
        int j = r & 7; r >>= 3; int L = r & 63; r >>= 6;
        int kc = r & 7, nt = r >> 3;
        row = kc * 32 + ((L >> 4) << 3) + j; col = nt * 16 + (L & 15);
        src = W1y; ld = WY;
    } else {                                           // W2y [256][64]
        r -= W2Y_OFF;
        int j = r & 7; r >>= 3; int L = r & 63; r >>= 6;
        int kc = r & 7, nt = r >> 3;
        row = kc * 32 + ((L >> 4) << 3) + j; col = nt * 16 + (L & 15);
        src = W2y; ld = DOUT;
    }
    ws[idx] = (bf16)src[row * ld + col];
}

// ---------------------------------------------------------------------------
// K1: recurrence. grid=16, block=512 (8 waves), <=256 VGPR (2 waves/EU).
// ---------------------------------------------------------------------------
__global__ __launch_bounds__(512, 2) void rnn_recur(
        const float* __restrict__ x, const float* __restrict__ b1h,
        const float* __restrict__ b2h, const bf16* __restrict__ ws,
        float* __restrict__ out) {
    // 131072 + 10752 + 16896 + 3072 = 161792 B <= 163840 B LDS
    __shared__ __align__(16) bf16  w2l[16 * 8 * 64 * 8]; // W2h kc8..15 frags, 128KB
    __shared__ __align__(16) bf16  hx_s[16 * HX_LD];     // [batch16][h256 | x64]
    __shared__ __align__(16) bf16  a1_s[16 * A1_LD];     // [batch16][512]
    __shared__ __align__(16) float bias_s[768];          // b1h(512) | b2h(256)

    const int tid = threadIdx.x;
    const int wv = tid >> 6, ln = tid & 63;
    const int quad = ln >> 4, l16 = ln & 15;
    const int wgb = blockIdx.x;
    float* hid = out + OUTS_N;

    // h0 = 0: zero LDS h-region ([0:256) only; x region staged every step)
    for (int i = tid; i < 16 * 256; i += 512) {
        int m = i >> 8, c = i & 255;
        hx_s[m * HX_LD + c] = (bf16)0.0f;
        hid[(wgb * 16 + m) * H + c] = 0.0f;
    }

    // biases -> LDS (per-step re-reads; __syncthreads blocks hoisting)
    bias_s[tid] = b1h[tid];
    if (tid < 256) bias_s[512 + tid] = b2h[tid];

    // stage W2h kc8..15 into LDS once: [nt16][kc8][lane][j8]
    for (int u = tid; u < 16 * 8 * 64; u += 512) {
        int nt = u >> 9, kc8 = (u >> 6) & 7, lu = u & 63;
        *(bf16x8*)(w2l + ((size_t)u << 3)) =
            *(const bf16x8*)(ws + W2H_OFF + (((nt * 16 + 8 + kc8) * 64 + lu) << 3));
    }

    // ---- PINNED resident weights ----
    // W1h kc6..9: wave wv owns mtiles {4wv..4wv+3} -> 64 VGPRs
    f32x4 w1r[4][4];
#pragma unroll
    for (int k = 0; k < 4; k++)
#pragma unroll
        for (int i = 0; i < 4; i++)
            w1r[k][i] = *(const f32x4*)(ws + W1H_OFF + ((((wv * 4 + i) * 10 + 6 + k) * 64 + ln) << 3));
    // W2h kc0..7: wave wv owns mtiles {2wv, 2wv+1} -> 64 VGPRs
    f32x4 w2f[8][2];
#pragma unroll
    for (int kc = 0; kc < 8; kc++)
#pragma unroll
        for (int i = 0; i < 2; i++)
            w2f[kc][i] = *(const f32x4*)(ws + W2H_OFF + ((((wv * 2 + i) * 16 + kc) * 64 + ln) << 3));
    // Pin: opaque definition -> compiler cannot rematerialize from memory.
#pragma unroll
    for (int k = 0; k < 4; k++)
#pragma unroll
        for (int i = 0; i < 4; i++) asm volatile("" : "+v"(w1r[k][i]));
#pragma unroll
    for (int kc = 0; kc < 8; kc++)
#pragma unroll
        for (int i = 0; i < 2; i++) asm volatile("" : "+v"(w2f[kc][i]));

    // x staging role: thread -> (row mrow, 2 contiguous x elements)
    const int mrow = tid >> 5;
    const int i2 = (tid & 31) * 2;
    const float* xrow = x + (size_t)(wgb * 16 + mrow) * (Sq * DIN) + i2;

    // streamed W1h kc0..5 via two rotating 4-frag buffers (32 VGPRs)
#define W1HP(i, kc) ((const f32x4*)(ws + W1H_OFF + ((((wv * 4 + (i)) * 10 + (kc)) * 64 + ln) << 3)))
    f32x4 sA[4], sB[4];
#pragma unroll
    for (int i = 0; i < 4; i++) sA[i] = *W1HP(i, 0);
#pragma unroll
    for (int i = 0; i < 4; i++) sB[i] = *W1HP(i, 1);

    float2 xv = *(const float2*)(xrow);   // x_0 prefetched
    f32x4 hprev[2];                        // h carried across barrier (b)
    float* hout = hid + HID_T + (size_t)(wgb * 16 + l16) * H + quad * 4;

#define LDHX(kc) (*(const bf16x8*)(hx_s + l16 * HX_LD + (kc) * 32 + quad * 8))
#define LDA1(kc) (*(const bf16x8*)(a1_s + l16 * A1_LD + (kc) * 32 + quad * 8))

#pragma unroll 1
    for (int t = 0; t < Sq; t++) {
        // stage prefetched x_t -> hx[:,256:320]
        bf16x2 xp; xp[0] = (bf16)xv.x; xp[1] = (bf16)xv.y;
        *(bf16x2*)(hx_s + mrow * HX_LD + 256 + i2) = xp;
        __syncthreads();   // (b): h + x staged, prior readers done

        // deferred h_t global store (drains at (d), hidden under GEMM1)
        if (t) {
#pragma unroll
            for (int i = 0; i < 2; i++)
                *(f32x4*)(hout + (2 * wv + i) * 16) = hprev[i];
            hout += HID_T;
        }
        // prefetch x_{t+1}
        xv = *(const float2*)(xrow + ((t + 1) & (Sq - 1)) * DIN);

        // ---- GEMM1 (swapped): z1^T = W1h^T hx^T ----
        // group order: s0 s1 r6 r7 s2 s3 r8 s4 r9 s5 (stream reloads >=3 groups ahead)
        f32x4 acc1[4];
#pragma unroll
        for (int i = 0; i < 4; i++)
            acc1[i] = *(const f32x4*)(bias_s + (wv * 4 + i) * 16 + quad * 4);
        bf16x8 a;
        a = LDHX(0);
#pragma unroll
        for (int i = 0; i < 4; i++) acc1[i] = MFMA16(bc8(sA[i]), a, acc1[i]);
#pragma unroll
        for (int i = 0; i < 4; i++) sA[i] = *W1HP(i, 2);
        a = LDHX(1);
#pragma unroll
        for (int i = 0; i < 4; i++) acc1[i] = MFMA16(bc8(sB[i]), a, acc1[i]);
#pragma unroll
        for (int i = 0; i < 4; i++) sB[i] = *W1HP(i, 3);
        a = LDHX(6);
#pragma unroll
        for (int i = 0; i < 4; i++) acc1[i] = MFMA16(bc8(w1r[0][i]), a, acc1[i]);
        a = LDHX(7);
#pragma unroll
        for (int i = 0; i < 4; i++) acc1[i] = MFMA16(bc8(w1r[1][i]), a, acc1[i]);
        a = LDHX(2);
#pragma unroll
        for (int i = 0; i < 4; i++) acc1[i] = MFMA16(bc8(sA[i]), a, acc1[i]);
#pragma unroll
        for (int i = 0; i < 4; i++) sA[i] = *W1HP(i, 4);
        a = LDHX(3);
#pragma unroll
        for (int i = 0; i < 4; i++) acc1[i] = MFMA16(bc8(sB[i]), a, acc1[i]);
#pragma unroll
        for (int i = 0; i < 4; i++) sB[i] = *W1HP(i, 5);
        a = LDHX(8);
#pragma unroll
        for (int i = 0; i < 4; i++) acc1[i] = MFMA16(bc8(w1r[2][i]), a, acc1[i]);
        a = LDHX(4);
#pragma unroll
        for (int i = 0; i < 4; i++) acc1[i] = MFMA16(bc8(sA[i]), a, acc1[i]);
        a = LDHX(9);
#pragma unroll
        for (int i = 0; i < 4; i++) acc1[i] = MFMA16(bc8(w1r[3][i]), a, acc1[i]);
        a = LDHX(5);
#pragma unroll
        for (int i = 0; i < 4; i++) acc1[i] = MFMA16(bc8(sB[i]), a, acc1[i]);

        // silu -> a1: one b64 write per i (4 consecutive cols of row l16)
#pragma unroll
        for (int i = 0; i < 4; i++)
            *(bf16x4*)(a1_s + l16 * A1_LD + (wv * 4 + i) * 16 + quad * 4) = silu4(acc1[i]);
        __syncthreads();   // (d): a1 complete, hx readers done

        // next step's streamed kc0/kc1 (whole GEMM2 of distance)
#pragma unroll
        for (int i = 0; i < 4; i++) sA[i] = *W1HP(i, 0);
#pragma unroll
        for (int i = 0; i < 4; i++) sB[i] = *W1HP(i, 1);

        // ---- GEMM2 (swapped): h^T = W2h^T a1^T ----
        f32x4 acc2[2];
#pragma unroll
        for (int i = 0; i < 2; i++)
            acc2[i] = *(const f32x4*)(bias_s + 512 + (wv * 2 + i) * 16 + quad * 4);
#pragma unroll
        for (int kc = 0; kc < 8; kc++) {
            a = LDA1(kc);
#pragma unroll
            for (int i = 0; i < 2; i++) acc2[i] = MFMA16(bc8(w2f[kc][i]), a, acc2[i]);
        }
#pragma unroll
        for (int kc = 8; kc < 16; kc++) {
            a = LDA1(kc);
#pragma unroll
            for (int i = 0; i < 2; i++) {
                bf16x8 b = *(const bf16x8*)(w2l + ((((wv * 2 + i) * 8 + (kc - 8)) * 64 + ln) << 3));
                acc2[i] = MFMA16(b, a, acc2[i]);
            }
        }

        // keep h for deferred global store; write bf16 h -> LDS for next step
#pragma unroll
        for (int i = 0; i < 2; i++) {
            hprev[i] = acc2[i];
            bf16x4 p; p[0] = (bf16)acc2[i][0]; p[1] = (bf16)acc2[i][1];
            p[2] = (bf16)acc2[i][2]; p[3] = (bf16)acc2[i][3];
            *(bf16x4*)(hx_s + l16 * HX_LD + (2 * wv + i) * 16 + quad * 4) = p;
        }
        // no barrier: next x-stage writes hx[:,256:320] (disjoint); (b) guards reads
    }
    // final h_Sq slab
#pragma unroll
    for (int i = 0; i < 2; i++)
        *(f32x4*)(hout + (2 * wv + i) * 16) = hprev[i];
#undef W1HP
#undef LDHX
#undef LDA1
}

// ---------------------------------------------------------------------------
// K2: output MLP over all (b,t). grid=4096 (b=g>>4, t0=(g&15)*64), block=256.
// (unchanged from R2 - validated)
// ---------------------------------------------------------------------------
__device__ __forceinline__ int swz8(int row) { return ((row ^ (row >> 3)) & 7) << 3; }

__global__ __launch_bounds__(256) void rnn_ymlp(
        const float* __restrict__ b1y, const float* __restrict__ b2y,
        const bf16* __restrict__ ws, float* __restrict__ out) {
    __shared__ __align__(16) bf16 hb[64 * 256];   // h rows, later a2 rows (swizzled)

    const int tid = threadIdx.x, wv = tid >> 6, ln = tid & 63;
    const int quad = ln >> 4, l16 = ln & 15;
    const int g = blockIdx.x, b = g >> 4, t0 = (g & 15) * 64;
    const float* hid = out + OUTS_N;

    {
        int r = tid >> 2, c0 = (tid & 3) * 64;
        const int swr = swz8(r);
        const float* srcr = hid + (size_t)(t0 + 1 + r) * HID_T + b * H + c0;
        bf16* drow = hb + r * 256;
#pragma unroll
        for (int jj = 0; jj < 16; jj++) {
            float4 v = *(const float4*)(srcr + jj * 4);
            bf16x4 p; p[0] = (bf16)v.x; p[1] = (bf16)v.y; p[2] = (bf16)v.z; p[3] = (bf16)v.w;
            *(bf16x4*)(drow + ((c0 + jj * 4) ^ swr)) = p;
        }
    }
    __syncthreads();

    f32x4 acc[4][4];
#pragma unroll
    for (int i = 0; i < 4; i++) {
        float4 v = *(const float4*)(b1y + (wv * 4 + i) * 16 + quad * 4);
        f32x4 bv; bv[0] = v.x; bv[1] = v.y; bv[2] = v.z; bv[3] = v.w;
#pragma unroll
        for (int nt = 0; nt < 4; nt++) acc[i][nt] = bv;
    }
#pragma unroll
    for (int kc = 0; kc < 8; kc++) {
        bf16x8 bb[4];
#pragma unroll
        for (int nt = 0; nt < 4; nt++) {
            int row = nt * 16 + l16;
            bb[nt] = *(const bf16x8*)(hb + row * 256 + ((kc * 32 + quad * 8) ^ swz8(row)));
        }
#pragma unroll
        for (int i = 0; i < 4; i++) {
            bf16x8 wf = *(const bf16x8*)(ws + W1Y_OFF + ((((wv * 4 + i) * 8 + kc) * 64 + ln) << 3));
#pragma unroll
            for (int nt = 0; nt < 4; nt++) acc[i][nt] = MFMA16(wf, bb[nt], acc[i][nt]);
        }
    }
    __syncthreads();

#pragma unroll
    for (int i = 0; i < 4; i++)
#pragma unroll
        for (int nt = 0; nt < 4; nt++) {
            int row = nt * 16 + l16;
            *(bf16x4*)(hb + row * 256 + ((((wv * 4 + i) * 16 + quad * 4)) ^ swz8(row))) = silu4(acc[i][nt]);
        }
    __syncthreads();

    f32x4 acy[4];
    {
        float4 v = *(const float4*)(b2y + wv * 16 + quad * 4);
        f32x4 bv; bv[0] = v.x; bv[1] = v.y; bv[2] = v.z; bv[3] = v.w;
#pragma unroll
        for (int nt = 0; nt < 4; nt++) acy[nt] = bv;
    }
#pragma unroll
    for (int kc = 0; kc < 8; kc++) {
        bf16x8 wf = *(const bf16x8*)(ws + W2Y_OFF + (((wv * 8 + kc) * 64 + ln) << 3));
#pragma unroll
        for (int nt = 0; nt < 4; nt++) {
            int row = nt * 16 + l16;
            bf16x8 aa = *(const bf16x8*)(hb + row * 256 + ((kc * 32 + quad * 8) ^ swz8(row)));
            acy[nt] = MFMA16(wf, aa, acy[nt]);
        }
    }
    float* ob = out + (size_t)b * (Sq * DOUT);
#pragma unroll
    for (int nt = 0; nt < 4; nt++) {
        float4 v; v.x = acy[nt][0]; v.y = acy[nt][1]; v.z = acy[nt][2]; v.w = acy[nt][3];
        *(float4*)(ob + (size_t)(t0 + nt * 16 + l16) * DOUT + wv * 16 + quad * 4) = v;
    }
}

// ---------------------------------------------------------------------------
extern "C" void kernel_launch(void* const* d_in, const int* in_sizes, int n_in,
                              void* d_out, int out_size, void* d_ws, size_t ws_size,
                              hipStream_t stream) {
    (void)in_sizes; (void)n_in; (void)out_size; (void)ws_size;
    const float* x   = (const float*)d_in[0];
    const float* W1h = (const float*)d_in[1];
    const float* b1h = (const float*)d_in[2];
    const float* W2h = (const float*)d_in[3];
    const float* b2h = (const float*)d_in[4];
    const float* W1y = (const float*)d_in[5];
    const float* b1y = (const float*)d_in[6];
    const float* W2y = (const float*)d_in[7];
    const float* b2y = (const float*)d_in[8];
    float* out = (float*)d_out;
    bf16* ws = (bf16*)d_ws;

    prep_pack<<<(PACK_TOTAL + 255) / 256, 256, 0, stream>>>(W1h, W2h, W1y, W2y, ws);
    rnn_recur<<<16, 512, 0, stream>>>(x, b1h, b2h, ws, out);
    rnn_ymlp<<<4096, 256, 0, stream>>>(b1y, b2y, ws, out);
}